// Round 3
// baseline (26587.701 us; speedup 1.0000x reference)
//
#include <hip/hip_runtime.h>
#include <cstdint>

#define B_  64
#define T_  4096
#define F_  100
#define H_  200
#define G_  600   // 3H
#define NT_ 320   // scan block: 5 waves, 2 columns per thread

typedef _Float16 half2_t __attribute__((ext_vector_type(2)));

__device__ __forceinline__ float sigmoidf_(float x) {
    return 1.0f / (1.0f + __expf(-x));
}
__device__ __forceinline__ float tanh_fast_(float x) {
    float e = __expf(-2.0f * x);
    return (1.0f - e) / (1.0f + e);
}

__device__ __forceinline__ float fdot2_(half2_t a, half2_t b, float c) {
#if __has_builtin(__builtin_amdgcn_fdot2)
    return __builtin_amdgcn_fdot2(a, b, c, false);
#else
    return fmaf((float)a.x, (float)b.x, fmaf((float)a.y, (float)b.y, c));
#endif
}

// ---------------- Phase 0: pack Wh (f32 [200,600]) -> half2 [100][600] ----------------
__global__ void prep_whp(const float* __restrict__ Wh, half2_t* __restrict__ whp) {
    int i = blockIdx.x * 256 + threadIdx.x;
    if (i < 100 * G_) {
        int k = i / G_, c = i - k * G_;
        half2_t v;
        v.x = (_Float16)Wh[(2 * k) * G_ + c];
        v.y = (_Float16)Wh[(2 * k + 1) * G_ + c];
        whp[i] = v;
    }
}

// ---------------- Phase 1: gi = x @ Wi + bi (fp32) ----------------
__global__ __launch_bounds__(640, 1)
void gi_kernel(const float* __restrict__ x, const float* __restrict__ Wi,
               const float* __restrict__ bi, float* __restrict__ gi,
               int t0, int TC) {
    __shared__ float xT[F_ * 68];
    int row0 = blockIdx.x * 64;
    int b    = row0 / TC;
    int tc0  = row0 - b * TC;
    const float* xrow = x + ((size_t)b * T_ + t0 + tc0) * F_;
    for (int i = threadIdx.x; i < 64 * F_; i += 640) {
        int r = i / F_, f = i - r * F_;
        xT[f * 68 + r] = xrow[i];
    }
    __syncthreads();
    int col = threadIdx.x < G_ ? threadIdx.x : G_ - 1;
    float acc[64];
    #pragma unroll
    for (int r = 0; r < 64; ++r) acc[r] = 0.f;
    for (int f = 0; f < F_; ++f) {
        float wi = Wi[f * G_ + col];
        const float4* xf = (const float4*)&xT[f * 68];
        #pragma unroll
        for (int q = 0; q < 16; ++q) {
            float4 v = xf[q];
            acc[4*q+0] = fmaf(v.x, wi, acc[4*q+0]);
            acc[4*q+1] = fmaf(v.y, wi, acc[4*q+1]);
            acc[4*q+2] = fmaf(v.z, wi, acc[4*q+2]);
            acc[4*q+3] = fmaf(v.w, wi, acc[4*q+3]);
        }
    }
    if (threadIdx.x < G_) {
        float bv = bi[col];
        float* grow = gi + (size_t)row0 * G_ + col;
        #pragma unroll 4
        for (int r = 0; r < 64; ++r) grow[(size_t)r * G_] = acc[r] + bv;
    }
}

// ---------------- Phase 2: sequential GRU scan ----------------
// 64 blocks (one per batch), 320 threads (5 waves). Thread t owns columns t and t+320,
// each as 100 packed half2 in ARCH VGPRs (~235 total < 256 cap at 2 waves/SIMD).
__global__ __launch_bounds__(NT_, 1)
void scan_kernel(const float* __restrict__ gi, const half2_t* __restrict__ whp,
                 const float* __restrict__ bhn, _Float16* __restrict__ hs,
                 float* __restrict__ hstate, int TC, int first) {
    __shared__ __align__(16) _Float16 h_h[208];   // h in f16, read as float4 broadcast
    __shared__ float A_lds[G_];
    __shared__ float Hn_lds[H_];
    int b = blockIdx.x;
    int tid = threadIdx.x;
    int c0 = tid;                  // in [0,320): always r/z range (<400)
    int c1 = tid + NT_;            // in [320,600) when valid
    bool has1 = (c1 < G_);
    int c1c = has1 ? c1 : (G_ - 1);

    half2_t wh0[100], wh1[100];
    #pragma unroll
    for (int k = 0; k < 100; ++k) {
        wh0[k] = whp[k * G_ + c0];      // coalesced
        wh1[k] = whp[k * G_ + c1c];
    }
    float bhn1 = (c1c >= 2 * H_) ? bhn[c1c - 2 * H_] : 0.f;

    float hj = 0.f;
    if (tid < H_) {
        hj = first ? 0.f : hstate[b * H_ + tid];
        h_h[tid] = (_Float16)hj;
    }
    if (tid >= H_ && tid < 208) h_h[tid] = (_Float16)0.f;
    __syncthreads();

    const float* gp0 = gi + (size_t)b * TC * G_ + c0;
    const float* gp1 = gi + (size_t)b * TC * G_ + c1c;
    _Float16* hsb = hs + (size_t)b * TC * H_;

    float g0 = gp0[0];
    float g1 = gp1[0];
    for (int tc = 0; tc < TC; ++tc) {
        // prefetch next step's gi (last-iter read runs 1 row past this batch's gi
        // region, which is still inside d_ws — value unused)
        float g0n = gp0[G_];
        float g1n = gp1[G_];
        gp0 += G_; gp1 += G_;

        float a00 = 0.f, a01 = 0.f, a10 = 0.f, a11 = 0.f;
        const float4* h4 = (const float4*)h_h;
        #pragma unroll
        for (int q = 0; q < 25; ++q) {
            float4 hv = h4[q];            // broadcast: all lanes same address
            half2_t* hp = (half2_t*)&hv;
            a00 = fdot2_(hp[0], wh0[4*q+0], a00);
            a01 = fdot2_(hp[1], wh0[4*q+1], a01);
            a00 = fdot2_(hp[2], wh0[4*q+2], a00);
            a01 = fdot2_(hp[3], wh0[4*q+3], a01);
            a10 = fdot2_(hp[0], wh1[4*q+0], a10);
            a11 = fdot2_(hp[1], wh1[4*q+1], a11);
            a10 = fdot2_(hp[2], wh1[4*q+2], a10);
            a11 = fdot2_(hp[3], wh1[4*q+3], a11);
        }
        float acc0 = a00 + a01;
        float acc1 = a10 + a11;

        A_lds[c0] = g0 + acc0;            // c0 < 400 always: r/z gate input
        if (has1) {
            if (c1 < 2 * H_) {
                A_lds[c1] = g1 + acc1;
            } else {
                A_lds[c1] = g1;
                Hn_lds[c1 - 2 * H_] = acc1 + bhn1;
            }
        }
        __syncthreads();
        if (tid < H_) {
            float r = sigmoidf_(A_lds[tid]);
            float z = sigmoidf_(A_lds[H_ + tid]);
            float n = tanh_fast_(A_lds[2 * H_ + tid] + r * Hn_lds[tid]);
            hj = n + z * (hj - n);
            h_h[tid] = (_Float16)hj;
            hsb[(size_t)tc * H_ + tid] = (_Float16)hj;
        }
        __syncthreads();
        g0 = g0n; g1 = g1n;
    }
    if (tid < H_) hstate[b * H_ + tid] = hj;
}

// ---------------- Phase 3: out = hs @ Wo + bo ----------------
__global__ __launch_bounds__(256, 4)
void outproj_kernel(const _Float16* __restrict__ hs, const float* __restrict__ Wo,
                    const float* __restrict__ bo, float* __restrict__ out,
                    int t0, int TC) {
    int r = blockIdx.x * 256 + threadIdx.x;
    if (r >= B_ * TC) return;
    int b = r / TC, tc = r - b * TC;
    const float4* h4 = (const float4*)(hs + (size_t)r * H_);
    float acc = 0.f;
    #pragma unroll
    for (int q = 0; q < 25; ++q) {
        float4 v = h4[q];
        const _Float16* hp = (const _Float16*)&v;
        #pragma unroll
        for (int j = 0; j < 8; ++j)
            acc = fmaf((float)hp[j], Wo[q * 8 + j], acc);
    }
    out[(size_t)b * T_ + t0 + tc] = acc + bo[0];
}

extern "C" void kernel_launch(void* const* d_in, const int* in_sizes, int n_in,
                              void* d_out, int out_size, void* d_ws, size_t ws_size,
                              hipStream_t stream) {
    const float* x   = (const float*)d_in[0];
    const float* Wi  = (const float*)d_in[1];
    const float* bi  = (const float*)d_in[2];
    const float* Wh  = (const float*)d_in[3];
    const float* bhn = (const float*)d_in[4];
    const float* Wo  = (const float*)d_in[5];
    const float* bo  = (const float*)d_in[6];
    float* out = (float*)d_out;

    const size_t hstate_b = (size_t)B_ * H_ * sizeof(float);
    const size_t whp_b    = (size_t)100 * G_ * sizeof(half2_t);
    // ws layout: [gi: B*TC*G*4][hs: B*TC*H*2][hstate][whp]
    int TC = T_;
    while (TC > 64 &&
           (size_t)B_ * TC * (G_ * 4 + H_ * 2) + hstate_b + whp_b > ws_size)
        TC >>= 1;
    char* p = (char*)d_ws;
    float*    gi     = (float*)p;            p += (size_t)B_ * TC * G_ * sizeof(float);
    _Float16* hsbuf  = (_Float16*)p;         p += (size_t)B_ * TC * H_ * sizeof(_Float16);
    float*    hstate = (float*)p;            p += hstate_b;
    half2_t*  whp    = (half2_t*)p;

    prep_whp<<<dim3((100 * G_ + 255) / 256), dim3(256), 0, stream>>>(Wh, whp);

    int nchunks = T_ / TC;
    for (int c = 0; c < nchunks; ++c) {
        int t0 = c * TC;
        gi_kernel<<<dim3(B_ * TC / 64), dim3(640), 0, stream>>>(x, Wi, bi, gi, t0, TC);
        scan_kernel<<<dim3(B_), dim3(NT_), 0, stream>>>(gi, whp, bhn, hsbuf,
                                                        hstate, TC, c == 0);
        outproj_kernel<<<dim3((B_ * TC + 255) / 256), dim3(256), 0, stream>>>(
            hsbuf, Wo, bo, out, t0, TC);
    }
}